// Round 12
// baseline (216.244 us; speedup 1.0000x reference)
//
#include <hip/hip_runtime.h>

typedef float f4 __attribute__((ext_vector_type(4)));
typedef float f32x4 __attribute__((ext_vector_type(4)));
typedef short bf16x8 __attribute__((ext_vector_type(8)));
typedef unsigned short u16x8 __attribute__((ext_vector_type(8)));

static __device__ __forceinline__ unsigned short f2bf(float f) {
    unsigned int x = __builtin_bit_cast(unsigned int, f);
    x = (x + 0x7fffu + ((x >> 16) & 1u)) >> 16;
    return (unsigned short)x;
}
static __device__ __forceinline__ float bf2f(unsigned short h) {
    unsigned int x = ((unsigned int)h) << 16;
    return __builtin_bit_cast(float, x);
}

// async 16B global->LDS DMA (LDS dest = wave-uniform base + lane*16)
static __device__ __forceinline__ void gll16(const unsigned short* g, unsigned short* l) {
    __builtin_amdgcn_global_load_lds(
        (__attribute__((address_space(1))) void*)(g),
        (__attribute__((address_space(3))) void*)(l), 16, 0, 0);
}

// LDS frag offset (shorts) for row r, true 16B-slot s (involution, both sides)
static __device__ __forceinline__ int fragoff(int r, int s) {
    return r * 32 + ((s ^ ((r >> 1) & 3)) << 3);
}

// ================= stage 1: merged {e,p} GEMM with in-staging f32->split-bf16
//                   conversion, + W_out conversion blocks in same launch
struct GJobF {
    const float *A, *W;
    int lda, ldw;
    const float* bias;
    unsigned short *Ch, *Cl;
    int N, K, nbx;
};

__global__ __launch_bounds__(256, 3) void gemmcvt64(
    GJobF j0, GJobF j1, int nblk0, int nblk1,
    const float* __restrict__ Wo, unsigned short* __restrict__ Wo_h,
    unsigned short* __restrict__ Wo_l, int nWo8)
{
    __shared__ unsigned short lds[2][4][64 * 32];   // 2 bufs x {Ah,Al,Wh,Wl}

    const int bid = blockIdx.x;
    const int tid = threadIdx.x;

    if (bid >= nblk0 + nblk1) {
        // ---- W_out f32 -> hi/lo planes (grid-stride over 8-elem chunks)
        const int nblkc = (int)gridDim.x - nblk0 - nblk1;
        for (int g = (bid - nblk0 - nblk1) * 256 + tid; g < nWo8; g += nblkc * 256) {
            const int idx = g * 8;
            f4 a = *(const f4*)(Wo + idx);
            f4 b = *(const f4*)(Wo + idx + 4);
            u16x8 hv, lv;
            float s[8] = { a.x, a.y, a.z, a.w, b.x, b.y, b.z, b.w };
            #pragma unroll
            for (int i = 0; i < 8; ++i) {
                unsigned short h = f2bf(s[i]);
                hv[i] = h;
                lv[i] = f2bf(s[i] - bf2f(h));
            }
            *(u16x8*)(Wo_h + idx) = hv;
            *(u16x8*)(Wo_l + idx) = lv;
        }
        return;
    }

    const bool first = bid < nblk0;
    const GJobF J = first ? j0 : j1;
    const int local = first ? bid : bid - nblk0;
    const int m0 = (local % J.nbx) * 64;
    const int n0 = (local / J.nbx) * 64;

    const int lane = tid & 63;
    const int wid  = tid >> 6;
    const int wr   = wid >> 1, wc = wid & 1;
    const int lrow = lane & 15;
    const int s    = lane >> 4;

    // staging map: thread -> (row 0..63, true slot 0..3); swizzled LDS write
    const int row  = tid >> 2, slot = tid & 3;
    const int woff = fragoff(row, slot);
    const float* pA = J.A + (size_t)(m0 + row) * J.lda + slot * 8;
    const float* pW = J.W + (size_t)(n0 + row) * J.ldw + slot * 8;

    f4 ra0, ra1, rw0, rw1;

#define LOADREGS(k0) do { \
    ra0 = *(const f4*)(pA + (k0));     ra1 = *(const f4*)(pA + (k0) + 4); \
    rw0 = *(const f4*)(pW + (k0));     rw1 = *(const f4*)(pW + (k0) + 4); \
} while (0)

#define CVTWRITE(buf) do { \
    u16x8 ha, la, hw, lw; \
    float sa[8] = { ra0.x, ra0.y, ra0.z, ra0.w, ra1.x, ra1.y, ra1.z, ra1.w }; \
    float sw[8] = { rw0.x, rw0.y, rw0.z, rw0.w, rw1.x, rw1.y, rw1.z, rw1.w }; \
    _Pragma("unroll") \
    for (int i = 0; i < 8; ++i) { \
        unsigned short h = f2bf(sa[i]); \
        ha[i] = h; la[i] = f2bf(sa[i] - bf2f(h)); \
        h = f2bf(sw[i]); \
        hw[i] = h; lw[i] = f2bf(sw[i] - bf2f(h)); \
    } \
    *(u16x8*)&lds[buf][0][woff] = ha; \
    *(u16x8*)&lds[buf][1][woff] = la; \
    *(u16x8*)&lds[buf][2][woff] = hw; \
    *(u16x8*)&lds[buf][3][woff] = lw; \
} while (0)

    f32x4 acc[2][2];
    #pragma unroll
    for (int i = 0; i < 2; ++i)
        #pragma unroll
        for (int j = 0; j < 2; ++j) acc[i][j] = (f32x4){0.f, 0.f, 0.f, 0.f};

    const int nt = J.K / 32;

    LOADREGS(0);
    CVTWRITE(0);
    __syncthreads();

    int cur = 0;
    for (int t = 0; t < nt; ++t) {
        if (t + 1 < nt) LOADREGS((t + 1) * 32);

        bf16x8 ah[2], al[2], wh[2], wl[2];
        #pragma unroll
        for (int i = 0; i < 2; ++i) {
            const int ra = wr * 32 + i * 16 + lrow;
            const int rw = wc * 32 + i * 16 + lrow;
            ah[i] = *(const bf16x8*)&lds[cur][0][fragoff(ra, s)];
            al[i] = *(const bf16x8*)&lds[cur][1][fragoff(ra, s)];
            wh[i] = *(const bf16x8*)&lds[cur][2][fragoff(rw, s)];
            wl[i] = *(const bf16x8*)&lds[cur][3][fragoff(rw, s)];
        }
        #pragma unroll
        for (int i = 0; i < 2; ++i)
            #pragma unroll
            for (int j = 0; j < 2; ++j) {
                acc[i][j] = __builtin_amdgcn_mfma_f32_16x16x32_bf16(ah[i], wh[j], acc[i][j], 0, 0, 0);
                acc[i][j] = __builtin_amdgcn_mfma_f32_16x16x32_bf16(ah[i], wl[j], acc[i][j], 0, 0, 0);
                acc[i][j] = __builtin_amdgcn_mfma_f32_16x16x32_bf16(al[i], wh[j], acc[i][j], 0, 0, 0);
            }

        if (t + 1 < nt) {
            CVTWRITE(cur ^ 1);
            __syncthreads();
            cur ^= 1;
        }
    }
#undef LOADREGS
#undef CVTWRITE

    // epilogue: split-bf16 planes out; C/D layout col=lane&15, row=(lane>>4)*4+r
    #pragma unroll
    for (int i = 0; i < 2; ++i) {
        const int rbase = m0 + wr * 32 + i * 16 + (lane >> 4) * 4;
        #pragma unroll
        for (int j = 0; j < 2; ++j) {
            const int col = n0 + wc * 32 + j * 16 + (lane & 15);
            const float bv = J.bias[col];
            #pragma unroll
            for (int r = 0; r < 4; ++r) {
                float v = acc[i][j][r] + bv;
                size_t off = (size_t)(rbase + r) * J.N + col;
                unsigned short h = f2bf(v);
                J.Ch[off] = h;
                J.Cl[off] = f2bf(v - bf2f(h));
            }
        }
    }
}

// ================= stage 2 (Y only): split-bf16 GEMM, planes in, f32 out
struct GJob {
    const unsigned short *Ah, *Al, *Wh, *Wl;
    int lda, ldw;
    const float* bias;
    float* Cf;
    int N, K, nbx;
};

__global__ __launch_bounds__(256, 3) void gemm64(GJob J)
{
    __shared__ unsigned short lds[2][4][64 * 32];

    const int local = blockIdx.x;
    const int m0 = (local % J.nbx) * 64;
    const int n0 = (local / J.nbx) * 64;

    const int tid  = threadIdx.x;
    const int lane = tid & 63;
    const int wid  = tid >> 6;
    const int wr   = wid >> 1, wc = wid & 1;
    const int lrow = lane & 15;
    const int s    = lane >> 4;

    // DMA staging: pre-swizzled global source slot, linear LDS dest
    const int srow  = wid * 16 + (lane >> 2);
    const int sslot = (lane & 3) ^ ((srow >> 1) & 3);
    const size_t gA = (size_t)(m0 + srow) * J.lda + sslot * 8;
    const size_t gW = (size_t)(n0 + srow) * J.ldw + sslot * 8;

    f32x4 acc[2][2];
    #pragma unroll
    for (int i = 0; i < 2; ++i)
        #pragma unroll
        for (int j = 0; j < 2; ++j) acc[i][j] = (f32x4){0.f, 0.f, 0.f, 0.f};

    const int nt = J.K / 32;

    gll16(J.Ah + gA, &lds[0][0][wid * 512]);
    gll16(J.Al + gA, &lds[0][1][wid * 512]);
    gll16(J.Wh + gW, &lds[0][2][wid * 512]);
    gll16(J.Wl + gW, &lds[0][3][wid * 512]);
    asm volatile("s_waitcnt vmcnt(0)" ::: "memory");
    __syncthreads();

    int cur = 0;
    for (int t = 0; t < nt; ++t) {
        if (t + 1 < nt) {
            const int k0 = (t + 1) * 32;
            gll16(J.Ah + gA + k0, &lds[cur ^ 1][0][wid * 512]);
            gll16(J.Al + gA + k0, &lds[cur ^ 1][1][wid * 512]);
            gll16(J.Wh + gW + k0, &lds[cur ^ 1][2][wid * 512]);
            gll16(J.Wl + gW + k0, &lds[cur ^ 1][3][wid * 512]);
        }

        bf16x8 ah[2], al[2], wh[2], wl[2];
        #pragma unroll
        for (int i = 0; i < 2; ++i) {
            const int ra = wr * 32 + i * 16 + lrow;
            const int rw = wc * 32 + i * 16 + lrow;
            ah[i] = *(const bf16x8*)&lds[cur][0][fragoff(ra, s)];
            al[i] = *(const bf16x8*)&lds[cur][1][fragoff(ra, s)];
            wh[i] = *(const bf16x8*)&lds[cur][2][fragoff(rw, s)];
            wl[i] = *(const bf16x8*)&lds[cur][3][fragoff(rw, s)];
        }
        #pragma unroll
        for (int i = 0; i < 2; ++i)
            #pragma unroll
            for (int j = 0; j < 2; ++j) {
                acc[i][j] = __builtin_amdgcn_mfma_f32_16x16x32_bf16(ah[i], wh[j], acc[i][j], 0, 0, 0);
                acc[i][j] = __builtin_amdgcn_mfma_f32_16x16x32_bf16(ah[i], wl[j], acc[i][j], 0, 0, 0);
                acc[i][j] = __builtin_amdgcn_mfma_f32_16x16x32_bf16(al[i], wh[j], acc[i][j], 0, 0, 0);
            }

        if (t + 1 < nt) {
            asm volatile("s_waitcnt vmcnt(0)" ::: "memory");
            __syncthreads();
            cur ^= 1;
        }
    }

    #pragma unroll
    for (int i = 0; i < 2; ++i) {
        const int rbase = m0 + wr * 32 + i * 16 + (lane >> 4) * 4;
        #pragma unroll
        for (int j = 0; j < 2; ++j) {
            const int col = n0 + wc * 32 + j * 16 + (lane & 15);
            #pragma unroll
            for (int r = 0; r < 4; ++r)
                J.Cf[(size_t)(rbase + r) * J.N + col] = acc[i][j][r];
        }
    }
}

// ================= stage 3: fused X-GEMM + broadcast-add + stream out
// One block = 8 bt-rows x full v=1024. X computed with W1 planes read
// directly L2->VGPR (no LDS staging; W1 hi+lo = 2 MB, L2-resident/XCD).
// Writes: 2 MB fully contiguous per block, nontemporal.
__global__ __launch_bounds__(256) void fused_xb(
    const unsigned short* __restrict__ e_h, const unsigned short* __restrict__ e_l,
    const unsigned short* __restrict__ W1h, const unsigned short* __restrict__ W1l,
    const float* __restrict__ b_out,
    const float* __restrict__ Y,
    float* __restrict__ out)
{
    __shared__ float Xs[8][1024];   // 32 KB

    const int tid  = threadIdx.x;
    const int lane = tid & 63;
    const int wid  = tid >> 6;
    const int bt0  = blockIdx.x * 8;
    const int b    = bt0 >> 8;          // T = 256
    const int nb   = wid * 256;         // wave's v-range

    // A rows: MFMA wants 16; rows 8..15 duplicate 0..7 (discarded in epilogue)
    const int arow = bt0 + ((lane & 15) & 7);
    const int koff = (lane >> 4) * 8;
    const unsigned short* pAh = e_h + (size_t)arow * 512 + koff;
    const unsigned short* pAl = e_l + (size_t)arow * 512 + koff;

    f32x4 acc[16];
    #pragma unroll
    for (int i = 0; i < 16; ++i) acc[i] = (f32x4){0.f, 0.f, 0.f, 0.f};

    for (int k0 = 0; k0 < 512; k0 += 32) {
        bf16x8 ah = *(const bf16x8*)(pAh + k0);
        bf16x8 al = *(const bf16x8*)(pAl + k0);
        #pragma unroll
        for (int nt = 0; nt < 16; ++nt) {
            const size_t wrow = (size_t)(nb + nt * 16 + (lane & 15)) * 1024 + k0 + koff;
            bf16x8 wh = *(const bf16x8*)(W1h + wrow);
            bf16x8 wl = *(const bf16x8*)(W1l + wrow);
            acc[nt] = __builtin_amdgcn_mfma_f32_16x16x32_bf16(ah, wh, acc[nt], 0, 0, 0);
            acc[nt] = __builtin_amdgcn_mfma_f32_16x16x32_bf16(ah, wl, acc[nt], 0, 0, 0);
            acc[nt] = __builtin_amdgcn_mfma_f32_16x16x32_bf16(al, wh, acc[nt], 0, 0, 0);
        }
    }

    // epilogue: X tile -> LDS with bias; C/D layout col=lane&15, row=(lane>>4)*4+r
    const int r0 = (lane >> 4) * 4;
    #pragma unroll
    for (int nt = 0; nt < 16; ++nt) {
        const int col = nb + nt * 16 + (lane & 15);
        const float bv = b_out[col];
        if (r0 < 8) {   // lanes 0..31 hold valid rows 0..7
            #pragma unroll
            for (int r = 0; r < 4; ++r)
                Xs[r0 + r][col] = acc[nt][r] + bv;
        }
    }
    __syncthreads();

    // write phase: out[(bt0+btl)][u][:] = Xs[btl][:] + Y[b][u][:]
    const f4* Y4 = (const f4*)Y + (size_t)b * 64 * 256;
    f4* O4 = (f4*)out + (size_t)bt0 * 64 * 256;
    for (int btl = 0; btl < 8; ++btl) {
        f4 x = *(const f4*)&Xs[btl][tid * 4];
        f4* rowp = O4 + (size_t)btl * 64 * 256;
        #pragma unroll 4
        for (int u = 0; u < 64; ++u) {
            f4 y = Y4[u * 256 + tid];
            f4 r = { x.x + y.x, x.y + y.y, x.z + y.z, x.w + y.w };
            __builtin_nontemporal_store(r, &rowp[u * 256 + tid]);
        }
    }
}

extern "C" void kernel_launch(void* const* d_in, const int* in_sizes, int n_in,
                              void* d_out, int out_size, void* d_ws, size_t ws_size,
                              hipStream_t stream) {
    (void)in_sizes; (void)n_in; (void)out_size; (void)ws_size;

    const int B = 8, T = 256, U = 64;
    const int ENC = 512, DEC = 640, J = 512, V = 1024;
    const int MT = B * T;   // 2048
    const int MU = B * U;   // 512

    const float* enc    = (const float*)d_in[0];
    const float* pred   = (const float*)d_in[1];
    const float* W_enc  = (const float*)d_in[2];
    const float* b_enc  = (const float*)d_in[3];
    const float* W_pred = (const float*)d_in[4];
    const float* b_pred = (const float*)d_in[5];
    const float* W_out  = (const float*)d_in[6];
    const float* b_out  = (const float*)d_in[7];
    float* out = (float*)d_out;

    const int n_Wo = V * 2 * J;   // 1048576
    const int n_e  = MT * J;      // 1048576
    const int n_p  = MU * J;      // 262144

    unsigned short* w = (unsigned short*)d_ws;
    unsigned short* Wo_h = w;
    unsigned short* Wo_l = Wo_h + n_Wo;
    unsigned short* e_h  = Wo_l + n_Wo;
    unsigned short* e_l  = e_h + n_e;
    unsigned short* p_h  = e_l + n_e;
    unsigned short* p_l  = p_h + n_p;
    float* ws_Y = (float*)(p_l + n_p);          // (MU, V)

    // 1) merged e + p GEMMs with in-staging conversion + W_out cvt blocks
    GJobF je = { enc,  W_enc,  ENC, ENC, b_enc,  e_h, e_l, J, ENC, MT / 64 };
    GJobF jp = { pred, W_pred, DEC, DEC, b_pred, p_h, p_l, J, DEC, MU / 64 };
    const int nbe = (MT / 64) * (J / 64);   // 256
    const int nbp = (MU / 64) * (J / 64);   // 64
    const int ncv = 64;
    gemmcvt64<<<nbe + nbp + ncv, 256, 0, stream>>>(
        je, jp, nbe, nbp, W_out, Wo_h, Wo_l, n_Wo / 8);

    // 2) Y = p @ W2^T (planes in, f32 out)
    GJob jy = { p_h, p_l, Wo_h + J, Wo_l + J, J, 2 * J, nullptr, ws_Y, V, J, MU / 64 };
    const int nby = (MU / 64) * (V / 64);   // 128
    gemm64<<<nby, 256, 0, stream>>>(jy);

    // 3) fused X-GEMM + broadcast + stream out (256 blocks, 1/CU)
    fused_xb<<<MT / 8, 256, 0, stream>>>(
        e_h, e_l, Wo_h, Wo_l, b_out, ws_Y, out);
}

// Round 13
// 131.894 us; speedup vs baseline: 1.6395x; 1.6395x over previous
//
#include <hip/hip_runtime.h>

typedef float f4 __attribute__((ext_vector_type(4)));
typedef float f32x4 __attribute__((ext_vector_type(4)));
typedef short bf16x8 __attribute__((ext_vector_type(8)));
typedef unsigned short u16x8 __attribute__((ext_vector_type(8)));

static __device__ __forceinline__ unsigned short f2bf(float f) {
    unsigned int x = __builtin_bit_cast(unsigned int, f);
    x = (x + 0x7fffu + ((x >> 16) & 1u)) >> 16;
    return (unsigned short)x;
}
static __device__ __forceinline__ float bf2f(unsigned short h) {
    unsigned int x = ((unsigned int)h) << 16;
    return __builtin_bit_cast(float, x);
}

// async 16B global->LDS DMA (LDS dest = wave-uniform base + lane*16)
static __device__ __forceinline__ void gll16(const unsigned short* g, unsigned short* l) {
    __builtin_amdgcn_global_load_lds(
        (__attribute__((address_space(1))) void*)(g),
        (__attribute__((address_space(3))) void*)(l), 16, 0, 0);
}

// LDS frag offset (shorts) for row r, true 16B-slot s (involution, both sides)
static __device__ __forceinline__ int fragoff(int r, int s) {
    return r * 32 + ((s ^ ((r >> 1) & 3)) << 3);
}

// ================= stage 1: merged {e,p} GEMM, A split hi+lo, W hi-only,
//                   in-staging f32->bf16 conversion + W_out cvt blocks
struct GJobF {
    const float *A, *W;
    int lda, ldw;
    const float* bias;
    unsigned short *Ch, *Cl;
    int N, K, nbx;
};

__global__ __launch_bounds__(256, 3) void gemmcvt64(
    GJobF j0, GJobF j1, int nblk0, int nblk1,
    const float* __restrict__ Wo, unsigned short* __restrict__ Wo_h, int nWo8)
{
    __shared__ unsigned short lds[2][3][64 * 32];   // 2 bufs x {Ah,Al,Wh}

    const int bid = blockIdx.x;
    const int tid = threadIdx.x;

    if (bid >= nblk0 + nblk1) {
        // ---- W_out f32 -> bf16 hi plane (grid-stride over 8-elem chunks)
        const int nblkc = (int)gridDim.x - nblk0 - nblk1;
        for (int g = (bid - nblk0 - nblk1) * 256 + tid; g < nWo8; g += nblkc * 256) {
            const int idx = g * 8;
            f4 a = *(const f4*)(Wo + idx);
            f4 b = *(const f4*)(Wo + idx + 4);
            u16x8 hv;
            float s[8] = { a.x, a.y, a.z, a.w, b.x, b.y, b.z, b.w };
            #pragma unroll
            for (int i = 0; i < 8; ++i) hv[i] = f2bf(s[i]);
            *(u16x8*)(Wo_h + idx) = hv;
        }
        return;
    }

    const bool first = bid < nblk0;
    const GJobF J = first ? j0 : j1;
    const int local = first ? bid : bid - nblk0;
    const int m0 = (local % J.nbx) * 64;
    const int n0 = (local / J.nbx) * 64;

    const int lane = tid & 63;
    const int wid  = tid >> 6;
    const int wr   = wid >> 1, wc = wid & 1;
    const int lrow = lane & 15;
    const int s    = lane >> 4;

    // staging map: thread -> (row 0..63, true slot 0..3); swizzled LDS write
    const int row  = tid >> 2, slot = tid & 3;
    const int woff = fragoff(row, slot);
    const float* pA = J.A + (size_t)(m0 + row) * J.lda + slot * 8;
    const float* pW = J.W + (size_t)(n0 + row) * J.ldw + slot * 8;

    f4 ra0, ra1, rw0, rw1;

#define LOADREGS(k0) do { \
    ra0 = *(const f4*)(pA + (k0));     ra1 = *(const f4*)(pA + (k0) + 4); \
    rw0 = *(const f4*)(pW + (k0));     rw1 = *(const f4*)(pW + (k0) + 4); \
} while (0)

#define CVTWRITE(buf) do { \
    u16x8 ha, la, hw; \
    float sa[8] = { ra0.x, ra0.y, ra0.z, ra0.w, ra1.x, ra1.y, ra1.z, ra1.w }; \
    float sw[8] = { rw0.x, rw0.y, rw0.z, rw0.w, rw1.x, rw1.y, rw1.z, rw1.w }; \
    _Pragma("unroll") \
    for (int i = 0; i < 8; ++i) { \
        unsigned short h = f2bf(sa[i]); \
        ha[i] = h; la[i] = f2bf(sa[i] - bf2f(h)); \
        hw[i] = f2bf(sw[i]); \
    } \
    *(u16x8*)&lds[buf][0][woff] = ha; \
    *(u16x8*)&lds[buf][1][woff] = la; \
    *(u16x8*)&lds[buf][2][woff] = hw; \
} while (0)

    f32x4 acc[2][2];
    #pragma unroll
    for (int i = 0; i < 2; ++i)
        #pragma unroll
        for (int j = 0; j < 2; ++j) acc[i][j] = (f32x4){0.f, 0.f, 0.f, 0.f};

    const int nt = J.K / 32;

    LOADREGS(0);
    CVTWRITE(0);
    __syncthreads();

    int cur = 0;
    for (int t = 0; t < nt; ++t) {
        if (t + 1 < nt) LOADREGS((t + 1) * 32);

        bf16x8 ah[2], al[2], wh[2];
        #pragma unroll
        for (int i = 0; i < 2; ++i) {
            const int ra = wr * 32 + i * 16 + lrow;
            const int rw = wc * 32 + i * 16 + lrow;
            ah[i] = *(const bf16x8*)&lds[cur][0][fragoff(ra, s)];
            al[i] = *(const bf16x8*)&lds[cur][1][fragoff(ra, s)];
            wh[i] = *(const bf16x8*)&lds[cur][2][fragoff(rw, s)];
        }
        #pragma unroll
        for (int i = 0; i < 2; ++i)
            #pragma unroll
            for (int j = 0; j < 2; ++j) {
                acc[i][j] = __builtin_amdgcn_mfma_f32_16x16x32_bf16(ah[i], wh[j], acc[i][j], 0, 0, 0);
                acc[i][j] = __builtin_amdgcn_mfma_f32_16x16x32_bf16(al[i], wh[j], acc[i][j], 0, 0, 0);
            }

        if (t + 1 < nt) {
            CVTWRITE(cur ^ 1);
            __syncthreads();
            cur ^= 1;
        }
    }
#undef LOADREGS
#undef CVTWRITE

    // epilogue: split-bf16 planes out; C/D layout col=lane&15, row=(lane>>4)*4+r
    #pragma unroll
    for (int i = 0; i < 2; ++i) {
        const int rbase = m0 + wr * 32 + i * 16 + (lane >> 4) * 4;
        #pragma unroll
        for (int j = 0; j < 2; ++j) {
            const int col = n0 + wc * 32 + j * 16 + (lane & 15);
            const float bv = J.bias[col];
            #pragma unroll
            for (int r = 0; r < 4; ++r) {
                float v = acc[i][j][r] + bv;
                size_t off = (size_t)(rbase + r) * J.N + col;
                unsigned short h = f2bf(v);
                J.Ch[off] = h;
                J.Cl[off] = f2bf(v - bf2f(h));
            }
        }
    }
}

// ================= stage 2: merged {X,Y} GEMM, A = hi+lo planes, W = hi only
//   64M x 128N tile, 2-buf DMA staging, f32 out.
struct GJob {
    const unsigned short *Ah, *Al, *Wh;
    int lda, ldw;
    const float* bias;
    float* Cf;
    int N, K, nbx;
};

__global__ __launch_bounds__(256, 4) void gemm64x128(GJob j0, GJob j1, int nblk0)
{
    // per buf: Ah 64x32, Al 64x32, Wh 128x32 shorts = 16 KB; 2 bufs = 32 KB
    __shared__ unsigned short lds[2][4][64 * 32];   // [buf][{Ah,Al,Wh0,Wh1}]

    const bool first = (int)blockIdx.x < nblk0;
    const GJob J = first ? j0 : j1;
    const int local = first ? (int)blockIdx.x : (int)blockIdx.x - nblk0;
    const int m0 = (local % J.nbx) * 64;
    const int n0 = (local / J.nbx) * 128;

    const int tid  = threadIdx.x;
    const int lane = tid & 63;
    const int wid  = tid >> 6;
    const int wr   = wid >> 1, wc = wid & 1;
    const int lrow = lane & 15;
    const int s    = lane >> 4;

    // DMA staging (per wave, 4 DMAs/step): A rows wid*16.., W rows wid*32..
    const int arow  = wid * 16 + (lane >> 2);
    const int aslot = (lane & 3) ^ ((arow >> 1) & 3);
    const size_t gA = (size_t)(m0 + arow) * J.lda + aslot * 8;
    const int wrow0 = wid * 32 + (lane >> 2);
    const int wrow1 = wrow0 + 16;
    const int wsl0  = (lane & 3) ^ ((wrow0 >> 1) & 3);
    const int wsl1  = (lane & 3) ^ ((wrow1 >> 1) & 3);
    const size_t gW0 = (size_t)(n0 + wrow0) * J.ldw + wsl0 * 8;
    const size_t gW1 = (size_t)(n0 + wrow1) * J.ldw + wsl1 * 8;

#define STAGE(buf, k0) do { \
    gll16(J.Ah + gA + (k0),  &lds[buf][0][wid * 512]); \
    gll16(J.Al + gA + (k0),  &lds[buf][1][wid * 512]); \
    gll16(J.Wh + gW0 + (k0), &lds[buf][2 + (wid >> 1)][(wid & 1) * 1024]); \
    gll16(J.Wh + gW1 + (k0), &lds[buf][2 + (wid >> 1)][(wid & 1) * 1024 + 512]); \
} while (0)

    f32x4 acc[2][4];
    #pragma unroll
    for (int i = 0; i < 2; ++i)
        #pragma unroll
        for (int j = 0; j < 4; ++j) acc[i][j] = (f32x4){0.f, 0.f, 0.f, 0.f};

    const int nt = J.K / 32;

    STAGE(0, 0);
    asm volatile("s_waitcnt vmcnt(0)" ::: "memory");
    __syncthreads();

    int cur = 0;
    for (int t = 0; t < nt; ++t) {
        if (t + 1 < nt) STAGE(cur ^ 1, (t + 1) * 32);

        bf16x8 ah[2], al[2], wh[4];
        #pragma unroll
        for (int i = 0; i < 2; ++i) {
            const int ra = wr * 32 + i * 16 + lrow;
            ah[i] = *(const bf16x8*)&lds[cur][0][fragoff(ra, s)];
            al[i] = *(const bf16x8*)&lds[cur][1][fragoff(ra, s)];
        }
        #pragma unroll
        for (int j = 0; j < 4; ++j) {
            const int rw = wc * 64 + j * 16 + lrow;   // 0..127 within W planes
            wh[j] = *(const bf16x8*)&lds[cur][2 + (rw >> 6)][fragoff(rw & 63, s)];
        }
        #pragma unroll
        for (int i = 0; i < 2; ++i)
            #pragma unroll
            for (int j = 0; j < 4; ++j) {
                acc[i][j] = __builtin_amdgcn_mfma_f32_16x16x32_bf16(ah[i], wh[j], acc[i][j], 0, 0, 0);
                acc[i][j] = __builtin_amdgcn_mfma_f32_16x16x32_bf16(al[i], wh[j], acc[i][j], 0, 0, 0);
            }

        if (t + 1 < nt) {
            asm volatile("s_waitcnt vmcnt(0)" ::: "memory");
            __syncthreads();
            cur ^= 1;
        }
    }
#undef STAGE

    #pragma unroll
    for (int i = 0; i < 2; ++i) {
        const int rbase = m0 + wr * 32 + i * 16 + (lane >> 4) * 4;
        #pragma unroll
        for (int j = 0; j < 4; ++j) {
            const int col = n0 + wc * 64 + j * 16 + (lane & 15);
            const float bv = J.bias ? J.bias[col] : 0.f;
            #pragma unroll
            for (int r = 0; r < 4; ++r)
                J.Cf[(size_t)(rbase + r) * J.N + col] = acc[i][j][r] + bv;
        }
    }
}

// ================= stage 3: out[(b,t),u,:] = X[(b,t),:] + Y[(b,u),:]
__global__ __launch_bounds__(256) void bcast_kernel(
    const float* __restrict__ X, const float* __restrict__ Y,
    float* __restrict__ out, int T, int U)
{
    const int Vq  = 256;           // 1024 / 4
    const int bt  = blockIdx.x;
    const int b   = bt / T;
    const int tid = threadIdx.x;

    const f4* X4 = (const f4*)X;
    const f4* Y4 = (const f4*)Y + (size_t)b * U * Vq;
    f4* O4 = (f4*)out + (size_t)bt * U * Vq;

    f4 x = X4[(size_t)bt * Vq + tid];
    #pragma unroll 4
    for (int u = 0; u < U; ++u) {
        f4 y = Y4[u * Vq + tid];
        f4 r = { x.x + y.x, x.y + y.y, x.z + y.z, x.w + y.w };
        __builtin_nontemporal_store(r, &O4[u * Vq + tid]);
    }
}

extern "C" void kernel_launch(void* const* d_in, const int* in_sizes, int n_in,
                              void* d_out, int out_size, void* d_ws, size_t ws_size,
                              hipStream_t stream) {
    (void)in_sizes; (void)n_in; (void)out_size; (void)ws_size;

    const int B = 8, T = 256, U = 64;
    const int ENC = 512, DEC = 640, J = 512, V = 1024;
    const int MT = B * T;   // 2048
    const int MU = B * U;   // 512

    const float* enc    = (const float*)d_in[0];
    const float* pred   = (const float*)d_in[1];
    const float* W_enc  = (const float*)d_in[2];
    const float* b_enc  = (const float*)d_in[3];
    const float* W_pred = (const float*)d_in[4];
    const float* b_pred = (const float*)d_in[5];
    const float* W_out  = (const float*)d_in[6];
    const float* b_out  = (const float*)d_in[7];
    float* out = (float*)d_out;

    const int n_Wo = V * 2 * J;   // 1048576
    const int n_e  = MT * J;      // 1048576
    const int n_p  = MU * J;      // 262144

    unsigned short* w = (unsigned short*)d_ws;
    unsigned short* Wo_h = w;                   // hi plane only
    unsigned short* e_h  = Wo_h + n_Wo;
    unsigned short* e_l  = e_h + n_e;
    unsigned short* p_h  = e_l + n_e;
    unsigned short* p_l  = p_h + n_p;
    float* ws_X = (float*)(p_l + n_p);          // (MT, V)
    float* ws_Y = ws_X + (size_t)MT * V;        // (MU, V)

    // 1) merged e + p GEMMs (A split, W hi-only) + W_out hi-cvt blocks
    GJobF je = { enc,  W_enc,  ENC, ENC, b_enc,  e_h, e_l, J, ENC, MT / 64 };
    GJobF jp = { pred, W_pred, DEC, DEC, b_pred, p_h, p_l, J, DEC, MU / 64 };
    const int nbe = (MT / 64) * (J / 64);   // 256
    const int nbp = (MU / 64) * (J / 64);   // 64
    const int ncv = 64;
    gemmcvt64<<<nbe + nbp + ncv, 256, 0, stream>>>(
        je, jp, nbe, nbp, W_out, Wo_h, n_Wo / 8);

    // 2) merged X + Y GEMMs (A planes + W hi), 64x128 tiles, f32 out
    GJob jx = { e_h, e_l, Wo_h,     J, 2 * J, b_out,   ws_X, V, J, MT / 64 };
    GJob jy = { p_h, p_l, Wo_h + J, J, 2 * J, nullptr, ws_Y, V, J, MU / 64 };
    const int nbx = (MT / 64) * (V / 128);   // 256
    const int nby = (MU / 64) * (V / 128);   // 64
    gemm64x128<<<nbx + nby, 256, 0, stream>>>(jx, jy, nbx);

    // 3) out = X broadcast + Y
    bcast_kernel<<<dim3(B * T), 256, 0, stream>>>(ws_X, ws_Y, out, T, U);
}